// Round 5
// baseline (1526.147 us; speedup 1.0000x reference)
//
#include <hip/hip_runtime.h>

// MeshSDFLoss: P=16384 points vs F=16384 triangles, min sqdist + argmin + loss.
// Outputs (flat float32): [0]=loss, [1..P]=dist, [1+P..1+2P]=assoc (as float).
//
// R5: hierarchical certified sphere pruning on Morton-sorted faces.
//  - Executed pairs BIT-EXACT vs numpy fp32 reference (__f*_rn chain, verified
//    R2: absmax 2.4e-7). Local/global best kept as packed u64
//    (distbits<<32)|origIdx and min'd -> np.argmin first-index tie-break
//    independent of execution order.
//  - Certified prune: dist(p,tri) >= |p-center| - radius (face and 32-face
//    group spheres), margins rel 1.001 + abs 1e-4. Skip => ref dist > bestd.
//  - SLIVER EXEMPTION (the R3/R4 bug): faces with |ab x ac|^2 < 3e-4 get
//    radius=+inf (group radius inherits inf) -> always executed exactly.
//    (R4 bug: rsqrtf(denormal nn)=inf -> pd=inf -> sliver force-SKIPPED.)
//    Also covers ref-vs-true distance divergence from garbage interior
//    barycentrics on tiny den_in.
//  - Seeds: 2 exact execs/block from the 8 sorted faces at the point's own
//    Morton position; cross-block sharing via atomicMin + periodic refresh.

#define PTOT 16384
#define FTOT 16384
#define NBINS 4096
#define BLOCK 256
#define GSIZE 32                  // faces per group
#define GTOT (FTOT / GSIZE)       // 512 groups
#define NCH 8                     // y-blocks per point-block
#define GPB (GTOT / NCH)          // 64 groups per block
#define QD 8                      // per-lane queue depth
#define SLIVER_NN 3e-4f

// ws layout (bytes)
#define WS_BEST    0          // u64[16384]            131072
#define WS_SORTP   131072     // uint4[16384]          262144
#define WS_HISTP   393216     // u32[4096]
#define WS_HISTF   409600     // u32[4096]
#define WS_HISTFC  425984     // u32[4096]
#define WS_FA      442368     // float4[16384] {a, origIdxBits}
#define WS_FB      704512     // float4[16384] {b, 0}
#define WS_FC      966656     // float4[16384] {c, 0}
#define WS_FS      1228800    // float4[16384] {centroid, rf}
#define WS_GRP     1490944    // float4[512]   {gc, gr}
// total ~1.43 MB

__device__ __forceinline__ unsigned morton12(float x, float y, float z) {
    int ix = (int)(x * 16.0f); ix = ix < 0 ? 0 : (ix > 15 ? 15 : ix);
    int iy = (int)(y * 16.0f); iy = iy < 0 ? 0 : (iy > 15 ? 15 : iy);
    int iz = (int)(z * 16.0f); iz = iz < 0 ? 0 : (iz > 15 ? 15 : iz);
    unsigned code = 0;
#pragma unroll
    for (int k = 0; k < 4; ++k) {
        code |= (((unsigned)(ix >> k) & 1u) << (3 * k + 2))
              | (((unsigned)(iy >> k) & 1u) << (3 * k + 1))
              | (((unsigned)(iz >> k) & 1u) << (3 * k + 0));
    }
    return code;
}

// Bit-exact point-triangle squared distance (reference-identical rounding).
__device__ __forceinline__ float exec_pair(
    float px, float py, float pz,
    float ax, float ay, float az,
    float bx, float by, float bz,
    float cx, float cy, float cz)
{
#pragma clang fp contract(off)
    const float abx = __fsub_rn(bx, ax), aby = __fsub_rn(by, ay), abz = __fsub_rn(bz, az);
    const float acx = __fsub_rn(cx, ax), acy = __fsub_rn(cy, ay), acz = __fsub_rn(cz, az);
    const float cbx = __fsub_rn(cx, bx), cby = __fsub_rn(cy, by), cbz = __fsub_rn(cz, bz);

    const float apx = __fsub_rn(px, ax), apy = __fsub_rn(py, ay), apz = __fsub_rn(pz, az);
    const float d1 = __fadd_rn(__fadd_rn(__fmul_rn(abx, apx), __fmul_rn(aby, apy)), __fmul_rn(abz, apz));
    const float d2 = __fadd_rn(__fadd_rn(__fmul_rn(acx, apx), __fmul_rn(acy, apy)), __fmul_rn(acz, apz));
    const float bpx = __fsub_rn(px, bx), bpy = __fsub_rn(py, by), bpz = __fsub_rn(pz, bz);
    const float d3 = __fadd_rn(__fadd_rn(__fmul_rn(abx, bpx), __fmul_rn(aby, bpy)), __fmul_rn(abz, bpz));
    const float d4 = __fadd_rn(__fadd_rn(__fmul_rn(acx, bpx), __fmul_rn(acy, bpy)), __fmul_rn(acz, bpz));
    const float cpx = __fsub_rn(px, cx), cpy = __fsub_rn(py, cy), cpz = __fsub_rn(pz, cz);
    const float d5 = __fadd_rn(__fadd_rn(__fmul_rn(abx, cpx), __fmul_rn(aby, cpy)), __fmul_rn(abz, cpz));
    const float d6 = __fadd_rn(__fadd_rn(__fmul_rn(acx, cpx), __fmul_rn(acy, cpy)), __fmul_rn(acz, cpz));

    const float vc_ = __fsub_rn(__fmul_rn(d1, d4), __fmul_rn(d3, d2));
    const float vb_ = __fsub_rn(__fmul_rn(d5, d2), __fmul_rn(d1, d6));
    const float va_ = __fsub_rn(__fmul_rn(d3, d6), __fmul_rn(d5, d4));

    const float den_ab = __fsub_rn(d1, d3);
    const float den_ac = __fsub_rn(d2, d6);
    const float t43    = __fsub_rn(d4, d3);
    const float t56    = __fsub_rn(d5, d6);
    const float den_bc = __fadd_rn(t43, t56);
    const float den_in = __fadd_rn(__fadd_rn(va_, vb_), vc_);

    const bool f_a  = (d1 <= 0.0f) && (d2 <= 0.0f);
    const bool f_b  = (d3 >= 0.0f) && (d4 <= d3);
    const bool f_c  = (d6 >= 0.0f) && (d5 <= d6);
    const bool f_ab = (vc_ <= 0.0f) && (d1 >= 0.0f) && (d3 <= 0.0f);
    const bool f_ac = (vb_ <= 0.0f) && (d2 >= 0.0f) && (d6 <= 0.0f);
    const bool f_bc = (va_ <= 0.0f) && (t43 >= 0.0f) && (t56 >= 0.0f);
    const bool vert = f_a || f_b || f_c;
    const bool e_ab = f_ab && !vert;
    const bool e_ac = f_ac && !vert && !f_ab;
    const bool e_bc = f_bc && !vert && !f_ab && !f_ac;
    const bool inte = !vert && !f_ab && !f_ac && !f_bc;

    const float num  = e_ab ? d1 : (e_ac ? d2 : (e_bc ? t43 : 1.0f));
    const float denr = e_ab ? den_ab : (e_ac ? den_ac : (e_bc ? den_bc : den_in));
    const float den  = (denr != 0.0f) ? denr : 1.0f;
    const float t    = __fdiv_rn(num, den);

    const float v_in = __fmul_rn(vb_, t);
    const float w_in = __fmul_rn(vc_, t);

    const float s1 = vert ? 0.0f : (inte ? v_in : t);
    const float s2 = inte ? w_in : 0.0f;
    const bool  sel_b = (!f_a && f_b) || e_bc;
    const bool  sel_c = !f_a && !f_b && f_c;
    const float e1x = e_ac ? acx : (e_bc ? cbx : abx);
    const float e1y = e_ac ? acy : (e_bc ? cby : aby);
    const float e1z = e_ac ? acz : (e_bc ? cbz : abz);
    const float bsx = sel_b ? bx : (sel_c ? cx : ax);
    const float bsy = sel_b ? by : (sel_c ? cy : ay);
    const float bsz = sel_b ? bz : (sel_c ? cz : az);
    const float qx = __fadd_rn(__fadd_rn(bsx, __fmul_rn(e1x, s1)), __fmul_rn(acx, s2));
    const float qy = __fadd_rn(__fadd_rn(bsy, __fmul_rn(e1y, s1)), __fmul_rn(acy, s2));
    const float qz = __fadd_rn(__fadd_rn(bsz, __fmul_rn(e1z, s1)), __fmul_rn(acz, s2));

    const float dxx = __fsub_rn(px, qx), dyy = __fsub_rn(py, qy), dzz = __fsub_rn(pz, qz);
    return __fadd_rn(__fadd_rn(__fmul_rn(dxx, dxx), __fmul_rn(dyy, dyy)), __fmul_rn(dzz, dzz));
}

// ---- prep: histograms (points: blocks 0..63, faces: blocks 64..127) ----
__global__ __launch_bounds__(BLOCK) void hist_both_kernel(
    const float* __restrict__ verts, const int* __restrict__ faces,
    const float* __restrict__ points,
    unsigned* __restrict__ histP, unsigned* __restrict__ histF)
{
    const int b = blockIdx.x;
    if (b < 64) {
        const int p = b * BLOCK + threadIdx.x;
        atomicAdd(&histP[morton12(points[p*3], points[p*3+1], points[p*3+2])], 1u);
    } else {
        const int f = (b - 64) * BLOCK + threadIdx.x;
        const int i0 = faces[f*3+0], i1 = faces[f*3+1], i2 = faces[f*3+2];
        const float mx = (verts[i0*3+0] + verts[i1*3+0] + verts[i2*3+0]) * (1.0f/3.0f);
        const float my = (verts[i0*3+1] + verts[i1*3+1] + verts[i2*3+1]) * (1.0f/3.0f);
        const float mz = (verts[i0*3+2] + verts[i1*3+2] + verts[i2*3+2]) * (1.0f/3.0f);
        atomicAdd(&histF[morton12(mx, my, mz)], 1u);
    }
}

// ---- prep: exclusive scans (block 0: points, block 1: faces + copy) ----
__global__ __launch_bounds__(256) void scan_both_kernel(
    unsigned* __restrict__ histP, unsigned* __restrict__ histF,
    unsigned* __restrict__ histFC)
{
    unsigned* h = (blockIdx.x == 0) ? histP : histF;
    __shared__ unsigned ps[256];
    const int t = threadIdx.x;
    unsigned local[16];
    unsigned run = 0;
#pragma unroll
    for (int i = 0; i < 16; ++i) { unsigned v = h[t*16+i]; local[i] = run; run += v; }
    ps[t] = run;
    __syncthreads();
    for (int off = 1; off < 256; off <<= 1) {
        unsigned v = (t >= off) ? ps[t - off] : 0u;
        __syncthreads();
        ps[t] += v;
        __syncthreads();
    }
    const unsigned base = (t == 0) ? 0u : ps[t-1];
#pragma unroll
    for (int i = 0; i < 16; ++i) {
        const unsigned off = base + local[i];
        h[t*16+i] = off;
        if (blockIdx.x == 1) histFC[t*16+i] = off;
    }
}

// ---- prep: scatter (points: blocks 0..63, faces: blocks 64..127) ----
__global__ __launch_bounds__(BLOCK) void scatter_both_kernel(
    const float* __restrict__ verts, const int* __restrict__ faces,
    const float* __restrict__ points,
    unsigned* __restrict__ histP, unsigned* __restrict__ histF,
    uint4* __restrict__ sortP,
    float4* __restrict__ fA, float4* __restrict__ fB,
    float4* __restrict__ fC, float4* __restrict__ fS)
{
    const int b = blockIdx.x;
    if (b < 64) {
        const int p = b * BLOCK + threadIdx.x;
        const float x = points[p*3], y = points[p*3+1], z = points[p*3+2];
        const unsigned pos = atomicAdd(&histP[morton12(x, y, z)], 1u);
        sortP[pos] = make_uint4(__float_as_uint(x), __float_as_uint(y),
                                __float_as_uint(z), (unsigned)p);
    } else {
        const int f = (b - 64) * BLOCK + threadIdx.x;
        const int i0 = faces[f*3+0], i1 = faces[f*3+1], i2 = faces[f*3+2];
        const float ax = verts[i0*3+0], ay = verts[i0*3+1], az = verts[i0*3+2];
        const float bx = verts[i1*3+0], by = verts[i1*3+1], bz = verts[i1*3+2];
        const float cx = verts[i2*3+0], cy = verts[i2*3+1], cz = verts[i2*3+2];
        const float mx = (ax+bx+cx) * (1.0f/3.0f);
        const float my = (ay+by+cy) * (1.0f/3.0f);
        const float mz = (az+bz+cz) * (1.0f/3.0f);
        const unsigned pos = atomicAdd(&histF[morton12(mx, my, mz)], 1u);
        fA[pos] = make_float4(ax, ay, az, __uint_as_float((unsigned)f));
        fB[pos] = make_float4(bx, by, bz, 0.0f);
        fC[pos] = make_float4(cx, cy, cz, 0.0f);
        // face bounding sphere (+ sliver exemption)
        const float abx = bx-ax, aby = by-ay, abz = bz-az;
        const float acx = cx-ax, acy = cy-ay, acz = cz-az;
        const float nx = aby*acz - abz*acy;
        const float ny = abz*acx - abx*acz;
        const float nz = abx*acy - aby*acx;
        const float nn = nx*nx + ny*ny + nz*nz;
        const float ra = sqrtf((ax-mx)*(ax-mx) + (ay-my)*(ay-my) + (az-mz)*(az-mz));
        const float rb = sqrtf((bx-mx)*(bx-mx) + (by-my)*(by-my) + (bz-mz)*(bz-mz));
        const float rc = sqrtf((cx-mx)*(cx-mx) + (cy-my)*(cy-my) + (cz-mz)*(cz-mz));
        float rf = fmaxf(ra, fmaxf(rb, rc)) * 1.001f + 1e-4f;
        if (!(nn >= SLIVER_NN)) rf = __builtin_inff();   // sliver/degenerate: never prune
        fS[pos] = make_float4(mx, my, mz, rf);
    }
}

// ---- prep: 32-face group spheres ----
__global__ __launch_bounds__(256) void group_kernel(
    const float4* __restrict__ fS, float4* __restrict__ grp)
{
    const int g = blockIdx.x * 256 + threadIdx.x;
    if (g >= GTOT) return;
    const int base = g * GSIZE;
    float sx = 0, sy = 0, sz = 0;
    for (int i = 0; i < GSIZE; ++i) {
        const float4 s = fS[base+i];
        sx += s.x; sy += s.y; sz += s.z;
    }
    const float gx = sx * (1.0f/GSIZE), gy = sy * (1.0f/GSIZE), gz = sz * (1.0f/GSIZE);
    float mr = 0.0f;
    for (int i = 0; i < GSIZE; ++i) {
        const float4 s = fS[base+i];
        const float d = sqrtf((s.x-gx)*(s.x-gx) + (s.y-gy)*(s.y-gy) + (s.z-gz)*(s.z-gz));
        mr = fmaxf(mr, d + s.w);   // inf rf propagates
    }
    grp[g] = make_float4(gx, gy, gz, mr * 1.001f + 1e-4f);
}

// ---- main ----
__global__ __launch_bounds__(BLOCK) void sdf_main_kernel(
    const uint4* __restrict__ sortP,
    const unsigned* __restrict__ histFC,
    const float4* __restrict__ fA, const float4* __restrict__ fB,
    const float4* __restrict__ fC, const float4* __restrict__ fS,
    const float4* __restrict__ grp,
    unsigned long long* __restrict__ best)
{
    __shared__ float4 sG[GPB];
    __shared__ unsigned sQ[QD * BLOCK];

    const int tid = threadIdx.x;
    const uint4 sp = sortP[blockIdx.x * BLOCK + tid];
    const float px = __uint_as_float(sp.x);
    const float py = __uint_as_float(sp.y);
    const float pz = __uint_as_float(sp.z);
    const int  pid = (int)sp.w;

    if (tid < GPB) sG[tid] = grp[blockIdx.y * GPB + tid];

    unsigned long long bestPk = ~0ull;

    // seeds: 2 faces from the point's own Morton window (8 sorted faces)
    {
        const unsigned code = morton12(px, py, pz);
        int lo = (int)histFC[code] - 4;
        lo = lo < 0 ? 0 : (lo > FTOT - 8 ? FTOT - 8 : lo);
        const int s1 = lo + (int)blockIdx.y;
        const int s2 = lo + (int)((blockIdx.y + 4) & 7);
#pragma unroll
        for (int s = 0; s < 2; ++s) {
            const int i = s ? s2 : s1;
            const float4 A = fA[i], B = fB[i], C = fC[i];
            const float d = exec_pair(px, py, pz, A.x, A.y, A.z, B.x, B.y, B.z, C.x, C.y, C.z);
            const unsigned long long pk =
                ((unsigned long long)__float_as_uint(d) << 32) | __float_as_uint(A.w);
            if (pk < bestPk) bestPk = pk;
        }
    }
    const unsigned long long old = atomicMin(&best[pid], bestPk);
    if (old < bestPk) bestPk = old;
    float pruneS = sqrtf(__uint_as_float((unsigned)(bestPk >> 32)));
    float thrS   = __fmaf_rn(pruneS, 1.001f, 1e-4f);

    __syncthreads();

    int cnt = 0;
    auto drain = [&]() {
        for (int k = 0; k < QD; ++k) {
            if (!__ballot(k < cnt)) break;
            if (k < cnt) {
                const unsigned fi = sQ[k * BLOCK + tid];
                const float4 A = fA[fi], B = fB[fi], C = fC[fi];
                const float d = exec_pair(px, py, pz, A.x, A.y, A.z, B.x, B.y, B.z, C.x, C.y, C.z);
                const unsigned long long pk =
                    ((unsigned long long)__float_as_uint(d) << 32) | __float_as_uint(A.w);
                if (pk < bestPk) {
                    bestPk = pk;
                    pruneS = fminf(pruneS, sqrtf(d));
                    thrS   = __fmaf_rn(pruneS, 1.001f, 1e-4f);
                }
            }
        }
        cnt = 0;
    };

    for (int g = 0; g < GPB; ++g) {
        if ((g & 15) == 15) {   // periodic cross-block refresh
            const unsigned long long gb =
                __hip_atomic_load(&best[pid], __ATOMIC_RELAXED, __HIP_MEMORY_SCOPE_AGENT);
            pruneS = fminf(pruneS, sqrtf(__uint_as_float((unsigned)(gb >> 32))));
            thrS   = __fmaf_rn(pruneS, 1.001f, 1e-4f);
        }
        const float4 G = sG[g];
        const float gdx = px - G.x, gdy = py - G.y, gdz = pz - G.z;
        const float grr = __fmaf_rn(gdx, gdx, __fmaf_rn(gdy, gdy, gdz * gdz));
        const float gt  = thrS + G.w;            // inf-safe
        const bool gpass = !(grr > gt * gt);
        if (__any(gpass)) {
            const int fb = (blockIdx.y * GPB + g) * GSIZE;
            for (int f = 0; f < GSIZE; ++f) {
                const float4 S = fS[fb + f];     // wave-uniform address
                const float dx = px - S.x, dy = py - S.y, dz = pz - S.z;
                const float rr = __fmaf_rn(dx, dx, __fmaf_rn(dy, dy, dz * dz));
                const float t  = thrS + S.w;
                if (!(rr > t * t)) { sQ[cnt * BLOCK + tid] = (unsigned)(fb + f); ++cnt; }
                if (__ballot(cnt >= QD)) drain();
            }
        }
    }
    drain();

    atomicMin(&best[pid], bestPk);
}

__global__ __launch_bounds__(BLOCK) void sdf_final_kernel(
    const unsigned long long* __restrict__ best, float* __restrict__ out)
{
    __shared__ float wsum[BLOCK / 64];
    const int p = blockIdx.x * BLOCK + threadIdx.x;
    const unsigned long long v = best[p];
    const float d = __uint_as_float((unsigned)(v >> 32));
    const int idx = (int)(unsigned)(v & 0xffffffffull);
    out[1 + p] = d;
    out[1 + PTOT + p] = (float)idx;

    float s = d;
    for (int off = 32; off > 0; off >>= 1) s += __shfl_down(s, off, 64);
    const int lane = threadIdx.x & 63;
    const int w = threadIdx.x >> 6;
    if (lane == 0) wsum[w] = s;
    __syncthreads();
    if (threadIdx.x == 0) {
        float tsum = 0.0f;
        for (int i = 0; i < BLOCK / 64; ++i) tsum += wsum[i];
        atomicAdd(&out[0], tsum);
    }
}

extern "C" void kernel_launch(void* const* d_in, const int* in_sizes, int n_in,
                              void* d_out, int out_size, void* d_ws, size_t ws_size,
                              hipStream_t stream) {
    const float* verts  = (const float*)d_in[0];
    const int*   faces  = (const int*)d_in[1];
    const float* points = (const float*)d_in[2];
    float* out = (float*)d_out;

    char* ws = (char*)d_ws;
    unsigned long long* best = (unsigned long long*)(ws + WS_BEST);
    uint4*    sortP  = (uint4*)(ws + WS_SORTP);
    unsigned* histP  = (unsigned*)(ws + WS_HISTP);
    unsigned* histF  = (unsigned*)(ws + WS_HISTF);
    unsigned* histFC = (unsigned*)(ws + WS_HISTFC);
    float4*   fA     = (float4*)(ws + WS_FA);
    float4*   fB     = (float4*)(ws + WS_FB);
    float4*   fC     = (float4*)(ws + WS_FC);
    float4*   fS     = (float4*)(ws + WS_FS);
    float4*   grp    = (float4*)(ws + WS_GRP);

    hipMemsetAsync(best, 0xFF, (size_t)PTOT * sizeof(unsigned long long), stream);
    hipMemsetAsync(histP, 0, 2 * (size_t)NBINS * sizeof(unsigned), stream); // histP+histF contiguous
    hipMemsetAsync(out, 0, sizeof(float), stream);

    hist_both_kernel<<<128, BLOCK, 0, stream>>>(verts, faces, points, histP, histF);
    scan_both_kernel<<<2, 256, 0, stream>>>(histP, histF, histFC);
    scatter_both_kernel<<<128, BLOCK, 0, stream>>>(verts, faces, points, histP, histF,
                                                   sortP, fA, fB, fC, fS);
    group_kernel<<<2, 256, 0, stream>>>(fS, grp);

    dim3 grid(PTOT / BLOCK, NCH);
    sdf_main_kernel<<<grid, BLOCK, 0, stream>>>(sortP, histFC, fA, fB, fC, fS, grp, best);
    sdf_final_kernel<<<PTOT / BLOCK, BLOCK, 0, stream>>>(best, out);
}

// Round 6
// 399.699 us; speedup vs baseline: 3.8182x; 3.8182x over previous
//
#include <hip/hip_runtime.h>

// MeshSDFLoss: P=16384 points vs F=16384 triangles, min sqdist + argmin + loss.
// Outputs (flat float32): [0]=loss, [1..P]=dist, [1+P..1+2P]=assoc (as float).
//
// R6: plane-band scan with CERTIFIED per-face inflation kp, drain-time sphere
// filter with certified kq, bit-exact exec (R2-verified __f*_rn chain).
//   ref q always lies in the face plane (any region branch, even fp-garbage
//   barycentrics) up to off-plane noise <= kp; so ref_dist >= |nh.(p-a)|-kp.
//   Sphere: ref_dist >= |p-c| - rf - kq*D^2 (kq covers in-plane fp jumps).
//   Degenerate faces: kp/kq clamp at 1e4 -> always candidates -> always
//   executed exactly. Tie-break: packed (distbits<<32)|origIdx u64 min ==
//   np.argmin first-index, order-free.

#define PTOT 16384
#define FTOT 16384
#define NBINS 4096
#define BLOCK 256
#define NCH 16
#define FCHUNK (FTOT / NCH)    // 1024
#define TILE 256
#define QD 16

// ws layout (bytes)
#define WS_BEST    0           // u64[16384]
#define WS_HISTF   131072      // u32[4096]
#define WS_HISTFC  147456      // u32[4096]
#define WS_FSCAN   163840      // float4[16384] {nhx,nhy,nhz,md0}
#define WS_FKP     425984      // float[16384]
#define WS_FA      491520      // float4[16384] {a, origIdxBits}
#define WS_FB      753664      // float4[16384]
#define WS_FC      1015808     // float4[16384]
#define WS_FSPH    1277952     // float4[16384] {c, rf}
#define WS_FKQ     1540096     // float[16384]

__device__ __forceinline__ unsigned morton12(float x, float y, float z) {
    int ix = (int)(x * 16.0f); ix = ix < 0 ? 0 : (ix > 15 ? 15 : ix);
    int iy = (int)(y * 16.0f); iy = iy < 0 ? 0 : (iy > 15 ? 15 : iy);
    int iz = (int)(z * 16.0f); iz = iz < 0 ? 0 : (iz > 15 ? 15 : iz);
    unsigned code = 0;
#pragma unroll
    for (int k = 0; k < 4; ++k) {
        code |= (((unsigned)(ix >> k) & 1u) << (3 * k + 2))
              | (((unsigned)(iy >> k) & 1u) << (3 * k + 1))
              | (((unsigned)(iz >> k) & 1u) << (3 * k + 0));
    }
    return code;
}

// Bit-exact point-triangle squared distance (reference-identical rounding).
__device__ __forceinline__ float exec_pair(
    float px, float py, float pz,
    float ax, float ay, float az,
    float bx, float by, float bz,
    float cx, float cy, float cz)
{
#pragma clang fp contract(off)
    const float abx = __fsub_rn(bx, ax), aby = __fsub_rn(by, ay), abz = __fsub_rn(bz, az);
    const float acx = __fsub_rn(cx, ax), acy = __fsub_rn(cy, ay), acz = __fsub_rn(cz, az);
    const float cbx = __fsub_rn(cx, bx), cby = __fsub_rn(cy, by), cbz = __fsub_rn(cz, bz);

    const float apx = __fsub_rn(px, ax), apy = __fsub_rn(py, ay), apz = __fsub_rn(pz, az);
    const float d1 = __fadd_rn(__fadd_rn(__fmul_rn(abx, apx), __fmul_rn(aby, apy)), __fmul_rn(abz, apz));
    const float d2 = __fadd_rn(__fadd_rn(__fmul_rn(acx, apx), __fmul_rn(acy, apy)), __fmul_rn(acz, apz));
    const float bpx = __fsub_rn(px, bx), bpy = __fsub_rn(py, by), bpz = __fsub_rn(pz, bz);
    const float d3 = __fadd_rn(__fadd_rn(__fmul_rn(abx, bpx), __fmul_rn(aby, bpy)), __fmul_rn(abz, bpz));
    const float d4 = __fadd_rn(__fadd_rn(__fmul_rn(acx, bpx), __fmul_rn(acy, bpy)), __fmul_rn(acz, bpz));
    const float cpx = __fsub_rn(px, cx), cpy = __fsub_rn(py, cy), cpz = __fsub_rn(pz, cz);
    const float d5 = __fadd_rn(__fadd_rn(__fmul_rn(abx, cpx), __fmul_rn(aby, cpy)), __fmul_rn(abz, cpz));
    const float d6 = __fadd_rn(__fadd_rn(__fmul_rn(acx, cpx), __fmul_rn(acy, cpy)), __fmul_rn(acz, cpz));

    const float vc_ = __fsub_rn(__fmul_rn(d1, d4), __fmul_rn(d3, d2));
    const float vb_ = __fsub_rn(__fmul_rn(d5, d2), __fmul_rn(d1, d6));
    const float va_ = __fsub_rn(__fmul_rn(d3, d6), __fmul_rn(d5, d4));

    const float den_ab = __fsub_rn(d1, d3);
    const float den_ac = __fsub_rn(d2, d6);
    const float t43    = __fsub_rn(d4, d3);
    const float t56    = __fsub_rn(d5, d6);
    const float den_bc = __fadd_rn(t43, t56);
    const float den_in = __fadd_rn(__fadd_rn(va_, vb_), vc_);

    const bool f_a  = (d1 <= 0.0f) && (d2 <= 0.0f);
    const bool f_b  = (d3 >= 0.0f) && (d4 <= d3);
    const bool f_c  = (d6 >= 0.0f) && (d5 <= d6);
    const bool f_ab = (vc_ <= 0.0f) && (d1 >= 0.0f) && (d3 <= 0.0f);
    const bool f_ac = (vb_ <= 0.0f) && (d2 >= 0.0f) && (d6 <= 0.0f);
    const bool f_bc = (va_ <= 0.0f) && (t43 >= 0.0f) && (t56 >= 0.0f);
    const bool vert = f_a || f_b || f_c;
    const bool e_ab = f_ab && !vert;
    const bool e_ac = f_ac && !vert && !f_ab;
    const bool e_bc = f_bc && !vert && !f_ab && !f_ac;
    const bool inte = !vert && !f_ab && !f_ac && !f_bc;

    const float num  = e_ab ? d1 : (e_ac ? d2 : (e_bc ? t43 : 1.0f));
    const float denr = e_ab ? den_ab : (e_ac ? den_ac : (e_bc ? den_bc : den_in));
    const float den  = (denr != 0.0f) ? denr : 1.0f;
    const float t    = __fdiv_rn(num, den);

    const float v_in = __fmul_rn(vb_, t);
    const float w_in = __fmul_rn(vc_, t);

    const float s1 = vert ? 0.0f : (inte ? v_in : t);
    const float s2 = inte ? w_in : 0.0f;
    const bool  sel_b = (!f_a && f_b) || e_bc;
    const bool  sel_c = !f_a && !f_b && f_c;
    const float e1x = e_ac ? acx : (e_bc ? cbx : abx);
    const float e1y = e_ac ? acy : (e_bc ? cby : aby);
    const float e1z = e_ac ? acz : (e_bc ? cbz : abz);
    const float bsx = sel_b ? bx : (sel_c ? cx : ax);
    const float bsy = sel_b ? by : (sel_c ? cy : ay);
    const float bsz = sel_b ? bz : (sel_c ? cz : az);
    const float qx = __fadd_rn(__fadd_rn(bsx, __fmul_rn(e1x, s1)), __fmul_rn(acx, s2));
    const float qy = __fadd_rn(__fadd_rn(bsy, __fmul_rn(e1y, s1)), __fmul_rn(acy, s2));
    const float qz = __fadd_rn(__fadd_rn(bsz, __fmul_rn(e1z, s1)), __fmul_rn(acz, s2));

    const float dxx = __fsub_rn(px, qx), dyy = __fsub_rn(py, qy), dzz = __fsub_rn(pz, qz);
    return __fadd_rn(__fadd_rn(__fmul_rn(dxx, dxx), __fmul_rn(dyy, dyy)), __fmul_rn(dzz, dzz));
}

__global__ __launch_bounds__(BLOCK) void hist_kernel(
    const float* __restrict__ verts, const int* __restrict__ faces,
    unsigned* __restrict__ histF)
{
    const int f = blockIdx.x * BLOCK + threadIdx.x;
    const int i0 = faces[f*3+0], i1 = faces[f*3+1], i2 = faces[f*3+2];
    const float mx = (verts[i0*3+0] + verts[i1*3+0] + verts[i2*3+0]) * (1.0f/3.0f);
    const float my = (verts[i0*3+1] + verts[i1*3+1] + verts[i2*3+1]) * (1.0f/3.0f);
    const float mz = (verts[i0*3+2] + verts[i1*3+2] + verts[i2*3+2]) * (1.0f/3.0f);
    atomicAdd(&histF[morton12(mx, my, mz)], 1u);
}

__global__ __launch_bounds__(256) void scan_kernel(
    unsigned* __restrict__ histF, unsigned* __restrict__ histFC)
{
    __shared__ unsigned ps[256];
    const int t = threadIdx.x;
    unsigned local[16];
    unsigned run = 0;
#pragma unroll
    for (int i = 0; i < 16; ++i) { unsigned v = histF[t*16+i]; local[i] = run; run += v; }
    ps[t] = run;
    __syncthreads();
    for (int off = 1; off < 256; off <<= 1) {
        unsigned v = (t >= off) ? ps[t - off] : 0u;
        __syncthreads();
        ps[t] += v;
        __syncthreads();
    }
    const unsigned base = (t == 0) ? 0u : ps[t-1];
#pragma unroll
    for (int i = 0; i < 16; ++i) {
        const unsigned off = base + local[i];
        histF[t*16+i] = off;
        histFC[t*16+i] = off;
    }
}

// Scatter + build certified per-face records (fp64 internals).
__global__ __launch_bounds__(BLOCK) void build_kernel(
    const float* __restrict__ verts, const int* __restrict__ faces,
    unsigned* __restrict__ histF,
    float4* __restrict__ fScan, float* __restrict__ fKp,
    float4* __restrict__ fA, float4* __restrict__ fB, float4* __restrict__ fC,
    float4* __restrict__ fSph, float* __restrict__ fKq)
{
    const int f = blockIdx.x * BLOCK + threadIdx.x;
    const int i0 = faces[f*3+0], i1 = faces[f*3+1], i2 = faces[f*3+2];
    const float ax = verts[i0*3+0], ay = verts[i0*3+1], az = verts[i0*3+2];
    const float bx = verts[i1*3+0], by = verts[i1*3+1], bz = verts[i1*3+2];
    const float cx = verts[i2*3+0], cy = verts[i2*3+1], cz = verts[i2*3+2];
    const float mx = (ax+bx+cx) * (1.0f/3.0f);
    const float my = (ay+by+cy) * (1.0f/3.0f);
    const float mz = (az+bz+cz) * (1.0f/3.0f);
    const unsigned pos = atomicAdd(&histF[morton12(mx, my, mz)], 1u);

    fA[pos] = make_float4(ax, ay, az, __uint_as_float((unsigned)f));
    fB[pos] = make_float4(bx, by, bz, 0.0f);
    fC[pos] = make_float4(cx, cy, cz, 0.0f);

    // fp64 certified metadata
    const double abx = (double)bx-ax, aby = (double)by-ay, abz = (double)bz-az;
    const double acx = (double)cx-ax, acy = (double)cy-ay, acz = (double)cz-az;
    const double cbx = (double)cx-bx, cby = (double)cy-by, cbz = (double)cz-bz;
    const double nx = aby*acz - abz*acy;
    const double ny = abz*acx - abx*acz;
    const double nz = abx*acy - aby*acx;
    const double nn = nx*nx + ny*ny + nz*nz;
    const double eab = sqrt(abx*abx + aby*aby + abz*abz);
    const double eac = sqrt(acx*acx + acy*acy + acz*acz);
    const double ecb = sqrt(cbx*cbx + cby*cby + cbz*cbz);
    const double maxe = fmax(eab, fmax(eac, ecb));
    const double mine = fmin(eab, fmin(eac, ecb));

    float4 sc;
    float kp, kq;
    if (nn > 0.0) {
        const double rin = 1.0 / sqrt(nn);
        sc.x = (float)(nx * rin);
        sc.y = (float)(ny * rin);
        sc.z = (float)(nz * rin);
        sc.w = (float)(-(nx*rin*ax + ny*rin*ay + nz*rin*az));
        kp = (float)fmin(1e4, 2e-5 * maxe*maxe*maxe / nn);
        const double inv_mine = (mine > 0.0) ? (3.5 / mine) : 1e30;
        kq = (float)fmin(1e4, 5e-6 * maxe*maxe * (eab + eac + inv_mine) / nn);
    } else {
        sc = make_float4(0.0f, 0.0f, 0.0f, 0.0f);   // pd=0 -> always in band
        kp = 1e4f; kq = 1e4f;
    }
    fScan[pos] = sc;
    fKp[pos] = kp;
    fKq[pos] = kq;

    const double ra = sqrt(((double)ax-mx)*((double)ax-mx) + ((double)ay-my)*((double)ay-my) + ((double)az-mz)*((double)az-mz));
    const double rb = sqrt(((double)bx-mx)*((double)bx-mx) + ((double)by-my)*((double)by-my) + ((double)bz-mz)*((double)bz-mz));
    const double rc = sqrt(((double)cx-mx)*((double)cx-mx) + ((double)cy-my)*((double)cy-my) + ((double)cz-mz)*((double)cz-mz));
    const float rf = (float)(fmax(ra, fmax(rb, rc)) * 1.0005 + 1e-5);
    fSph[pos] = make_float4(mx, my, mz, rf);
}

__global__ __launch_bounds__(BLOCK) void sdf_main_kernel(
    const float* __restrict__ points,
    const unsigned* __restrict__ histFC,
    const float4* __restrict__ fScan, const float* __restrict__ fKp,
    const float4* __restrict__ fA, const float4* __restrict__ fB,
    const float4* __restrict__ fC, const float4* __restrict__ fSph,
    const float* __restrict__ fKq,
    unsigned long long* __restrict__ best)
{
    __shared__ float4 sScan[TILE];
    __shared__ float  sKp[TILE];
    __shared__ float4 sA[TILE], sB[TILE], sC[TILE];
    __shared__ float4 sSph[TILE];
    __shared__ float  sKq[TILE];
    __shared__ unsigned short sQ[TILE * QD];

    const int tid = threadIdx.x;
    const int p = blockIdx.x * BLOCK + tid;
    const float px = points[p*3+0];
    const float py = points[p*3+1];
    const float pz = points[p*3+2];

    // --- inline seed: 1 exact exec from the point's Morton face window ---
    unsigned long long bestPk = ~0ull;
    {
        const unsigned code = morton12(px, py, pz);
        int w = (int)histFC[code] - 1;
        w = w < 0 ? 0 : (w > FTOT - 2 ? FTOT - 2 : w);
        const int i = w + (int)(blockIdx.y & 1);
        const float4 A = fA[i], B = fB[i], C = fC[i];
        const float d = exec_pair(px, py, pz, A.x, A.y, A.z, B.x, B.y, B.z, C.x, C.y, C.z);
        bestPk = ((unsigned long long)__float_as_uint(d) << 32) | __float_as_uint(A.w);
    }
    {
        const unsigned long long old = atomicMin(&best[p], bestPk);
        if (old < bestPk) bestPk = old;
    }
    float pruneS = sqrtf(__uint_as_float((unsigned)(bestPk >> 32)));
    float thr    = __fmaf_rn(pruneS, 1.005f, 1e-3f);

    const int fbase = blockIdx.y * FCHUNK;
    int cnt = 0;

    auto drain = [&]() {
        for (int k = 0; k < cnt; ++k) {
            const int j = (int)sQ[tid * QD + k];
            const float4 S = sSph[j];
            const float dx = px - S.x, dy = py - S.y, dz = pz - S.z;
            const float dc = sqrtf(__fmaf_rn(dx, dx, __fmaf_rn(dy, dy, dz * dz)));
            const float D  = dc + S.w;
            // certified sphere skip: ref_dist >= dc - rf - kq*D^2
            if (dc > thr + S.w + sKq[j] * D * D) continue;
            const float4 A = sA[j], B = sB[j], C = sC[j];
            const float d = exec_pair(px, py, pz, A.x, A.y, A.z, B.x, B.y, B.z, C.x, C.y, C.z);
            const unsigned long long pk =
                ((unsigned long long)__float_as_uint(d) << 32) | __float_as_uint(A.w);
            if (pk < bestPk) {
                bestPk = pk;
                pruneS = fminf(pruneS, sqrtf(d));
                thr    = __fmaf_rn(pruneS, 1.005f, 1e-3f);
            }
        }
        cnt = 0;
    };

    for (int t0 = 0; t0 < FCHUNK; t0 += TILE) {
        __syncthreads();
        {
            const int g = fbase + t0 + tid;
            sScan[tid] = fScan[g];
            sKp[tid]   = fKp[g];
            sA[tid]    = fA[g];
            sB[tid]    = fB[g];
            sC[tid]    = fC[g];
            sSph[tid]  = fSph[g];
            sKq[tid]   = fKq[g];
        }
        __syncthreads();

        // fold in cross-chunk progress
        {
            const unsigned long long gb =
                __hip_atomic_load(&best[p], __ATOMIC_RELAXED, __HIP_MEMORY_SCOPE_AGENT);
            if (gb < bestPk) bestPk = gb;
            pruneS = fminf(pruneS, sqrtf(__uint_as_float((unsigned)(bestPk >> 32))));
            thr    = __fmaf_rn(pruneS, 1.005f, 1e-3f);
        }

        for (int j0 = 0; j0 < TILE; j0 += 8) {
#pragma unroll
            for (int j = j0; j < j0 + 8; ++j) {
                const float4 sc = sScan[j];
                const float pd = __fmaf_rn(sc.x, px, __fmaf_rn(sc.y, py, __fmaf_rn(sc.z, pz, sc.w)));
                // NaN-safe: candidate unless certified out of plane band
                const bool far = fabsf(pd) > (thr + sKp[j]);
                if (!far) { sQ[tid * QD + cnt] = (unsigned short)j; ++cnt; }
            }
            if (__any(cnt >= QD - 8)) drain();
        }
        drain();
    }

    atomicMin(&best[p], bestPk);
}

__global__ __launch_bounds__(BLOCK) void sdf_final_kernel(
    const unsigned long long* __restrict__ best, float* __restrict__ out)
{
    __shared__ float wsum[BLOCK / 64];
    const int p = blockIdx.x * BLOCK + threadIdx.x;
    const unsigned long long v = best[p];
    const float d = __uint_as_float((unsigned)(v >> 32));
    const int idx = (int)(unsigned)(v & 0xffffffffull);
    out[1 + p] = d;
    out[1 + PTOT + p] = (float)idx;

    float s = d;
    for (int off = 32; off > 0; off >>= 1) s += __shfl_down(s, off, 64);
    const int lane = threadIdx.x & 63;
    const int w = threadIdx.x >> 6;
    if (lane == 0) wsum[w] = s;
    __syncthreads();
    if (threadIdx.x == 0) {
        float tsum = 0.0f;
        for (int i = 0; i < BLOCK / 64; ++i) tsum += wsum[i];
        atomicAdd(&out[0], tsum);
    }
}

extern "C" void kernel_launch(void* const* d_in, const int* in_sizes, int n_in,
                              void* d_out, int out_size, void* d_ws, size_t ws_size,
                              hipStream_t stream) {
    const float* verts  = (const float*)d_in[0];
    const int*   faces  = (const int*)d_in[1];
    const float* points = (const float*)d_in[2];
    float* out = (float*)d_out;

    char* ws = (char*)d_ws;
    unsigned long long* best = (unsigned long long*)(ws + WS_BEST);
    unsigned* histF  = (unsigned*)(ws + WS_HISTF);
    unsigned* histFC = (unsigned*)(ws + WS_HISTFC);
    float4* fScan = (float4*)(ws + WS_FSCAN);
    float*  fKp   = (float*)(ws + WS_FKP);
    float4* fA    = (float4*)(ws + WS_FA);
    float4* fB    = (float4*)(ws + WS_FB);
    float4* fC    = (float4*)(ws + WS_FC);
    float4* fSph  = (float4*)(ws + WS_FSPH);
    float*  fKq   = (float*)(ws + WS_FKQ);

    hipMemsetAsync(best, 0xFF, (size_t)PTOT * sizeof(unsigned long long), stream);
    hipMemsetAsync(histF, 0, (size_t)NBINS * sizeof(unsigned), stream);
    hipMemsetAsync(out, 0, sizeof(float), stream);

    hist_kernel<<<FTOT / BLOCK, BLOCK, 0, stream>>>(verts, faces, histF);
    scan_kernel<<<1, 256, 0, stream>>>(histF, histFC);
    build_kernel<<<FTOT / BLOCK, BLOCK, 0, stream>>>(verts, faces, histF,
        fScan, fKp, fA, fB, fC, fSph, fKq);

    dim3 grid(PTOT / BLOCK, NCH);
    sdf_main_kernel<<<grid, BLOCK, 0, stream>>>(points, histFC,
        fScan, fKp, fA, fB, fC, fSph, fKq, best);
    sdf_final_kernel<<<PTOT / BLOCK, BLOCK, 0, stream>>>(best, out);
}

// Round 7
// 371.240 us; speedup vs baseline: 4.1109x; 1.0767x over previous
//
#include <hip/hip_runtime.h>
#include <math.h>

// MeshSDFLoss: P=16384 points vs F=16384 triangles, min sqdist + argmin + loss.
// Outputs (flat float32): [0]=loss, [1..P]=dist, [1+P..1+2P]=assoc (as float).
//
// R7: certified-by-error-analysis pruning.
//  - exec_pair: BIT-EXACT vs numpy fp32 reference (R2-verified).
//  - Scan: plane band. ref q always lies in span{a,ab,ac}; off-plane fp error
//    <= 36*eps*maxe^3/nn for non-exempt faces -> ref_d >= |pd| - kp with
//    kp = 3e-5*maxe^3/nn + 2e-5 (7x margin).
//  - Drain: ref_d >= true_d - J;  true_d^2 >= (|pd|-1e-5)+^2 + lat+^2
//    (lat = in-plane distance to face circumdisc). J bounds |q_ref - q_true|:
//    interior (6e-5*maxe^3/nn) + edge-t (5e-5*maxe^2/mine^2) + boundary
//    misselection (2.6e-6*maxe/mine + 3.2e-3 curvature floor), x1.2.
//  - Exempt faces (fp-noise-dominated denominators: nn < 1e-5*maxe^2 or
//    mine^2 < 5e-6*maxe): kp=1e4, J=1e30 -> always executed (~tens of faces).
//  - Tie-break: packed (distbits<<32)|origIdx u64 min == np.argmin
//    first-index, order-free. Skipped face certified ref_d > thr >= final
//    best -> can never be (or tie) the argmin.

#define PTOT 16384
#define FTOT 16384
#define NBINS 4096
#define BLOCK 256
#define NCH 16
#define FCHUNK (FTOT / NCH)   // 1024
#define TILE 256
#define QD 16

// ws layout (bytes)
#define WS_BEST    0           // u64[16384]   131072
#define WS_SORTP   131072      // uint4[16384] 262144
#define WS_HISTP   393216      // u32[4096]
#define WS_HISTF   409600      // u32[4096]
#define WS_HISTFC  425984      // u32[4096]
#define WS_FA      442368      // float4[16384] {a, origIdxBits}
#define WS_FB      704512      // float4[16384]
#define WS_FC      966656      // float4[16384]
#define WS_FSPH    1228800     // float4[16384] {centroid, rf}
#define WS_FSCAN   1490944     // float4[16384] {nh, md0}
#define WS_FK      1753088     // float2[16384] {kp, J}

__device__ __forceinline__ unsigned morton12(float x, float y, float z) {
    int ix = (int)(x * 16.0f); ix = ix < 0 ? 0 : (ix > 15 ? 15 : ix);
    int iy = (int)(y * 16.0f); iy = iy < 0 ? 0 : (iy > 15 ? 15 : iy);
    int iz = (int)(z * 16.0f); iz = iz < 0 ? 0 : (iz > 15 ? 15 : iz);
    unsigned code = 0;
#pragma unroll
    for (int k = 0; k < 4; ++k) {
        code |= (((unsigned)(ix >> k) & 1u) << (3 * k + 2))
              | (((unsigned)(iy >> k) & 1u) << (3 * k + 1))
              | (((unsigned)(iz >> k) & 1u) << (3 * k + 0));
    }
    return code;
}

// Bit-exact point-triangle squared distance (reference-identical rounding).
__device__ __forceinline__ float exec_pair(
    float px, float py, float pz,
    float ax, float ay, float az,
    float bx, float by, float bz,
    float cx, float cy, float cz)
{
#pragma clang fp contract(off)
    const float abx = __fsub_rn(bx, ax), aby = __fsub_rn(by, ay), abz = __fsub_rn(bz, az);
    const float acx = __fsub_rn(cx, ax), acy = __fsub_rn(cy, ay), acz = __fsub_rn(cz, az);
    const float cbx = __fsub_rn(cx, bx), cby = __fsub_rn(cy, by), cbz = __fsub_rn(cz, bz);

    const float apx = __fsub_rn(px, ax), apy = __fsub_rn(py, ay), apz = __fsub_rn(pz, az);
    const float d1 = __fadd_rn(__fadd_rn(__fmul_rn(abx, apx), __fmul_rn(aby, apy)), __fmul_rn(abz, apz));
    const float d2 = __fadd_rn(__fadd_rn(__fmul_rn(acx, apx), __fmul_rn(acy, apy)), __fmul_rn(acz, apz));
    const float bpx = __fsub_rn(px, bx), bpy = __fsub_rn(py, by), bpz = __fsub_rn(pz, bz);
    const float d3 = __fadd_rn(__fadd_rn(__fmul_rn(abx, bpx), __fmul_rn(aby, bpy)), __fmul_rn(abz, bpz));
    const float d4 = __fadd_rn(__fadd_rn(__fmul_rn(acx, bpx), __fmul_rn(acy, bpy)), __fmul_rn(acz, bpz));
    const float cpx = __fsub_rn(px, cx), cpy = __fsub_rn(py, cy), cpz = __fsub_rn(pz, cz);
    const float d5 = __fadd_rn(__fadd_rn(__fmul_rn(abx, cpx), __fmul_rn(aby, cpy)), __fmul_rn(abz, cpz));
    const float d6 = __fadd_rn(__fadd_rn(__fmul_rn(acx, cpx), __fmul_rn(acy, cpy)), __fmul_rn(acz, cpz));

    const float vc_ = __fsub_rn(__fmul_rn(d1, d4), __fmul_rn(d3, d2));
    const float vb_ = __fsub_rn(__fmul_rn(d5, d2), __fmul_rn(d1, d6));
    const float va_ = __fsub_rn(__fmul_rn(d3, d6), __fmul_rn(d5, d4));

    const float den_ab = __fsub_rn(d1, d3);
    const float den_ac = __fsub_rn(d2, d6);
    const float t43    = __fsub_rn(d4, d3);
    const float t56    = __fsub_rn(d5, d6);
    const float den_bc = __fadd_rn(t43, t56);
    const float den_in = __fadd_rn(__fadd_rn(va_, vb_), vc_);

    const bool f_a  = (d1 <= 0.0f) && (d2 <= 0.0f);
    const bool f_b  = (d3 >= 0.0f) && (d4 <= d3);
    const bool f_c  = (d6 >= 0.0f) && (d5 <= d6);
    const bool f_ab = (vc_ <= 0.0f) && (d1 >= 0.0f) && (d3 <= 0.0f);
    const bool f_ac = (vb_ <= 0.0f) && (d2 >= 0.0f) && (d6 <= 0.0f);
    const bool f_bc = (va_ <= 0.0f) && (t43 >= 0.0f) && (t56 >= 0.0f);
    const bool vert = f_a || f_b || f_c;
    const bool e_ab = f_ab && !vert;
    const bool e_ac = f_ac && !vert && !f_ab;
    const bool e_bc = f_bc && !vert && !f_ab && !f_ac;
    const bool inte = !vert && !f_ab && !f_ac && !f_bc;

    const float num  = e_ab ? d1 : (e_ac ? d2 : (e_bc ? t43 : 1.0f));
    const float denr = e_ab ? den_ab : (e_ac ? den_ac : (e_bc ? den_bc : den_in));
    const float den  = (denr != 0.0f) ? denr : 1.0f;
    const float t    = __fdiv_rn(num, den);

    const float v_in = __fmul_rn(vb_, t);
    const float w_in = __fmul_rn(vc_, t);

    const float s1 = vert ? 0.0f : (inte ? v_in : t);
    const float s2 = inte ? w_in : 0.0f;
    const bool  sel_b = (!f_a && f_b) || e_bc;
    const bool  sel_c = !f_a && !f_b && f_c;
    const float e1x = e_ac ? acx : (e_bc ? cbx : abx);
    const float e1y = e_ac ? acy : (e_bc ? cby : aby);
    const float e1z = e_ac ? acz : (e_bc ? cbz : abz);
    const float bsx = sel_b ? bx : (sel_c ? cx : ax);
    const float bsy = sel_b ? by : (sel_c ? cy : ay);
    const float bsz = sel_b ? bz : (sel_c ? cz : az);
    const float qx = __fadd_rn(__fadd_rn(bsx, __fmul_rn(e1x, s1)), __fmul_rn(acx, s2));
    const float qy = __fadd_rn(__fadd_rn(bsy, __fmul_rn(e1y, s1)), __fmul_rn(acy, s2));
    const float qz = __fadd_rn(__fadd_rn(bsz, __fmul_rn(e1z, s1)), __fmul_rn(acz, s2));

    const float dxx = __fsub_rn(px, qx), dyy = __fsub_rn(py, qy), dzz = __fsub_rn(pz, qz);
    return __fadd_rn(__fadd_rn(__fmul_rn(dxx, dxx), __fmul_rn(dyy, dyy)), __fmul_rn(dzz, dzz));
}

// ---- prep: histograms (blocks 0..63: points, 64..127: faces) ----
__global__ __launch_bounds__(BLOCK) void hist_kernel(
    const float* __restrict__ verts, const int* __restrict__ faces,
    const float* __restrict__ points,
    unsigned* __restrict__ histP, unsigned* __restrict__ histF)
{
    const int b = blockIdx.x;
    if (b < 64) {
        const int p = b * BLOCK + threadIdx.x;
        atomicAdd(&histP[morton12(points[p*3], points[p*3+1], points[p*3+2])], 1u);
    } else {
        const int f = (b - 64) * BLOCK + threadIdx.x;
        const int i0 = faces[f*3+0], i1 = faces[f*3+1], i2 = faces[f*3+2];
        const float mx = (verts[i0*3+0] + verts[i1*3+0] + verts[i2*3+0]) * (1.0f/3.0f);
        const float my = (verts[i0*3+1] + verts[i1*3+1] + verts[i2*3+1]) * (1.0f/3.0f);
        const float mz = (verts[i0*3+2] + verts[i1*3+2] + verts[i2*3+2]) * (1.0f/3.0f);
        atomicAdd(&histF[morton12(mx, my, mz)], 1u);
    }
}

__global__ __launch_bounds__(256) void scan_kernel(
    unsigned* __restrict__ histP, unsigned* __restrict__ histF,
    unsigned* __restrict__ histFC)
{
    unsigned* h = (blockIdx.x == 0) ? histP : histF;
    __shared__ unsigned ps[256];
    const int t = threadIdx.x;
    unsigned local[16];
    unsigned run = 0;
#pragma unroll
    for (int i = 0; i < 16; ++i) { unsigned v = h[t*16+i]; local[i] = run; run += v; }
    ps[t] = run;
    __syncthreads();
    for (int off = 1; off < 256; off <<= 1) {
        unsigned v = (t >= off) ? ps[t - off] : 0u;
        __syncthreads();
        ps[t] += v;
        __syncthreads();
    }
    const unsigned base = (t == 0) ? 0u : ps[t-1];
#pragma unroll
    for (int i = 0; i < 16; ++i) {
        const unsigned off = base + local[i];
        h[t*16+i] = off;
        if (blockIdx.x == 1) histFC[t*16+i] = off;
    }
}

// ---- prep: scatter points + scatter/build faces (fp64 certified metadata) ----
__global__ __launch_bounds__(BLOCK) void scatter_build_kernel(
    const float* __restrict__ verts, const int* __restrict__ faces,
    const float* __restrict__ points,
    unsigned* __restrict__ histP, unsigned* __restrict__ histF,
    uint4* __restrict__ sortP,
    float4* __restrict__ fA, float4* __restrict__ fB, float4* __restrict__ fC,
    float4* __restrict__ fSph, float4* __restrict__ fScan,
    float2* __restrict__ fK)
{
    const int b = blockIdx.x;
    if (b < 64) {
        const int p = b * BLOCK + threadIdx.x;
        const float x = points[p*3], y = points[p*3+1], z = points[p*3+2];
        const unsigned pos = atomicAdd(&histP[morton12(x, y, z)], 1u);
        sortP[pos] = make_uint4(__float_as_uint(x), __float_as_uint(y),
                                __float_as_uint(z), (unsigned)p);
        return;
    }
    const int f = (b - 64) * BLOCK + threadIdx.x;
    const int i0 = faces[f*3+0], i1 = faces[f*3+1], i2 = faces[f*3+2];
    const float ax = verts[i0*3+0], ay = verts[i0*3+1], az = verts[i0*3+2];
    const float bx = verts[i1*3+0], by = verts[i1*3+1], bz = verts[i1*3+2];
    const float cx = verts[i2*3+0], cy = verts[i2*3+1], cz = verts[i2*3+2];
    const float mx = (ax+bx+cx) * (1.0f/3.0f);
    const float my = (ay+by+cy) * (1.0f/3.0f);
    const float mz = (az+bz+cz) * (1.0f/3.0f);
    const unsigned pos = atomicAdd(&histF[morton12(mx, my, mz)], 1u);

    fA[pos] = make_float4(ax, ay, az, __uint_as_float((unsigned)f));
    fB[pos] = make_float4(bx, by, bz, 0.0f);
    fC[pos] = make_float4(cx, cy, cz, 0.0f);

    const double abx = (double)bx-ax, aby = (double)by-ay, abz = (double)bz-az;
    const double acx = (double)cx-ax, acy = (double)cy-ay, acz = (double)cz-az;
    const double cbx = (double)cx-bx, cby = (double)cy-by, cbz = (double)cz-bz;
    const double nx = aby*acz - abz*acy;
    const double ny = abz*acx - abx*acz;
    const double nz = abx*acy - aby*acx;
    const double nn = nx*nx + ny*ny + nz*nz;
    const double e1 = sqrt(abx*abx + aby*aby + abz*abz);
    const double e2 = sqrt(acx*acx + acy*acy + acz*acz);
    const double e3 = sqrt(cbx*cbx + cby*cby + cbz*cbz);
    const double maxe = fmax(e1, fmax(e2, e3));
    const double mine = fmin(e1, fmin(e2, e3));
    const double mine2 = mine * mine;
    const double maxe2 = maxe * maxe;
    const double maxe3 = maxe2 * maxe;

    const bool exempt = !(nn > 1e-5 * maxe2) || !(mine2 > 5e-6 * maxe);

    float4 sc;
    float kp, J;
    if (!exempt) {
        const double rin = 1.0 / sqrt(nn);
        sc.x = (float)(nx * rin);
        sc.y = (float)(ny * rin);
        sc.z = (float)(nz * rin);
        sc.w = (float)(-(nx*rin*ax + ny*rin*ay + nz*rin*az));
        kp = (float)fmin(1e4, 3e-5 * maxe3 / nn + 2e-5);
        J  = (float)fmin(1e4, 1.2 * (6e-5 * maxe3 / nn
                                   + 5e-5 * maxe2 / mine2
                                   + 2.6e-6 * maxe / mine
                                   + 3.2e-3));
    } else {
        sc = make_float4(0.0f, 0.0f, 0.0f, 0.0f);  // pd=0 -> always in band
        kp = 1e4f;
        J  = 1e30f;                                 // never drain-skipped
    }
    fScan[pos] = sc;
    fK[pos] = make_float2(kp, J);

    const double ra = sqrt(((double)ax-mx)*((double)ax-mx) + ((double)ay-my)*((double)ay-my) + ((double)az-mz)*((double)az-mz));
    const double rb = sqrt(((double)bx-mx)*((double)bx-mx) + ((double)by-my)*((double)by-my) + ((double)bz-mz)*((double)bz-mz));
    const double rc = sqrt(((double)cx-mx)*((double)cx-mx) + ((double)cy-my)*((double)cy-my) + ((double)cz-mz)*((double)cz-mz));
    const float rf = (float)(fmax(ra, fmax(rb, rc)) * 1.0002 + 2e-4);
    fSph[pos] = make_float4(mx, my, mz, rf);
}

// ---- main ----
__global__ __launch_bounds__(BLOCK) void sdf_main_kernel(
    const uint4* __restrict__ sortP,
    const unsigned* __restrict__ histFC,
    const float4* __restrict__ fA, const float4* __restrict__ fB,
    const float4* __restrict__ fC, const float4* __restrict__ fSph,
    const float4* __restrict__ fScan, const float2* __restrict__ fK,
    unsigned long long* __restrict__ best)
{
    __shared__ float4 sScan[TILE], sSph[TILE], sA[TILE], sB[TILE], sC[TILE];
    __shared__ float2 sK[TILE];
    __shared__ unsigned short sQ[TILE * QD];

    const int tid = threadIdx.x;
    const uint4 sp = sortP[blockIdx.x * BLOCK + tid];
    const float px = __uint_as_float(sp.x);
    const float py = __uint_as_float(sp.y);
    const float pz = __uint_as_float(sp.z);
    const int  pid = (int)sp.w;

    // --- seed: 2 faces of the 32-face Morton window (chunks jointly cover it) ---
    unsigned long long bestPk = ~0ull;
    {
        const unsigned code = morton12(px, py, pz);
        int w = (int)histFC[code] - 16;
        w = w < 0 ? 0 : (w > FTOT - 32 ? FTOT - 32 : w);
#pragma unroll
        for (int s = 0; s < 2; ++s) {
            const int i = w + 2 * (int)blockIdx.y + s;
            const float4 A = fA[i], B = fB[i], C = fC[i];
            const float d = exec_pair(px, py, pz, A.x, A.y, A.z, B.x, B.y, B.z, C.x, C.y, C.z);
            const unsigned long long pk =
                ((unsigned long long)__float_as_uint(d) << 32) | __float_as_uint(A.w);
            if (pk < bestPk) bestPk = pk;
        }
    }
    {
        const unsigned long long old = atomicMin(&best[pid], bestPk);
        if (old < bestPk) bestPk = old;
    }
    float pruneS = sqrtf(__uint_as_float((unsigned)(bestPk >> 32)));
    float thr    = __fmaf_rn(pruneS, 1.005f, 1e-3f);

    const int fbase = (int)blockIdx.y * FCHUNK;
    int cnt = 0;

    auto drain = [&]() {
        for (int k = 0; ; ++k) {
            if (!__ballot(k < cnt)) break;
            if (k < cnt) {
                const int j = (int)sQ[tid * QD + k];
                const float4 sc = sScan[j];
                const float4 S  = sSph[j];
                const float dx = px - S.x, dy = py - S.y, dz = pz - S.z;
                const float dcc2 = __fmaf_rn(dx, dx, __fmaf_rn(dy, dy, dz * dz));
                const float pdc  = __fmaf_rn(sc.x, dx, __fmaf_rn(sc.y, dy, sc.z * dz));
                const float pd   = __fmaf_rn(sc.x, px, __fmaf_rn(sc.y, py, __fmaf_rn(sc.z, pz, sc.w)));
                const float aa   = fmaxf(fabsf(pd) - 1e-5f, 0.0f);
                const float lat2 = fmaxf(dcc2 - pdc * pdc, 0.0f);
                const float lat  = fmaxf(sqrtf(lat2) * 0.999f - S.w - 1e-4f, 0.0f);
                const float lhs  = __fmaf_rn(aa, aa, lat * lat);
                const float rhs  = thr + sK[j].y;   // thr + J (inf-safe)
                // NaN lhs/rhs -> compare false -> execute (conservative)
                if (!(lhs > rhs * rhs)) {
                    const float4 A = sA[j], B = sB[j], C = sC[j];
                    const float d = exec_pair(px, py, pz, A.x, A.y, A.z, B.x, B.y, B.z, C.x, C.y, C.z);
                    const unsigned long long pk =
                        ((unsigned long long)__float_as_uint(d) << 32) | __float_as_uint(A.w);
                    if (pk < bestPk) {
                        bestPk = pk;
                        pruneS = fminf(pruneS, sqrtf(d));
                        thr    = __fmaf_rn(pruneS, 1.005f, 1e-3f);
                    }
                }
            }
        }
        cnt = 0;
    };

    for (int t0 = 0; t0 < FCHUNK; t0 += TILE) {
        __syncthreads();
        {
            const int g = fbase + t0 + tid;
            sScan[tid] = fScan[g];
            sSph[tid]  = fSph[g];
            sK[tid]    = fK[g];
            sA[tid]    = fA[g];
            sB[tid]    = fB[g];
            sC[tid]    = fC[g];
        }
        __syncthreads();

        // fold in cross-chunk progress
        {
            const unsigned long long gb =
                __hip_atomic_load(&best[pid], __ATOMIC_RELAXED, __HIP_MEMORY_SCOPE_AGENT);
            if (gb < bestPk) bestPk = gb;
            pruneS = fminf(pruneS, sqrtf(__uint_as_float((unsigned)(bestPk >> 32))));
            thr    = __fmaf_rn(pruneS, 1.005f, 1e-3f);
        }

        for (int j0 = 0; j0 < TILE; j0 += 8) {
#pragma unroll
            for (int j = j0; j < j0 + 8; ++j) {
                const float4 sc = sScan[j];
                const float pd = __fmaf_rn(sc.x, px, __fmaf_rn(sc.y, py, __fmaf_rn(sc.z, pz, sc.w)));
                // NaN-safe: NaN pd -> in band -> queued
                const bool inband = !(fabsf(pd) > (thr + sK[j].x));
                if (inband) { sQ[tid * QD + cnt] = (unsigned short)j; ++cnt; }
            }
            if (__any(cnt >= QD - 8)) drain();
        }
        drain();
    }

    atomicMin(&best[pid], bestPk);
}

__global__ __launch_bounds__(BLOCK) void sdf_final_kernel(
    const unsigned long long* __restrict__ best, float* __restrict__ out)
{
    __shared__ float wsum[BLOCK / 64];
    const int p = blockIdx.x * BLOCK + threadIdx.x;
    const unsigned long long v = best[p];
    const float d = __uint_as_float((unsigned)(v >> 32));
    const int idx = (int)(unsigned)(v & 0xffffffffull);
    out[1 + p] = d;
    out[1 + PTOT + p] = (float)idx;

    float s = d;
    for (int off = 32; off > 0; off >>= 1) s += __shfl_down(s, off, 64);
    const int lane = threadIdx.x & 63;
    const int w = threadIdx.x >> 6;
    if (lane == 0) wsum[w] = s;
    __syncthreads();
    if (threadIdx.x == 0) {
        float tsum = 0.0f;
        for (int i = 0; i < BLOCK / 64; ++i) tsum += wsum[i];
        atomicAdd(&out[0], tsum);
    }
}

extern "C" void kernel_launch(void* const* d_in, const int* in_sizes, int n_in,
                              void* d_out, int out_size, void* d_ws, size_t ws_size,
                              hipStream_t stream) {
    const float* verts  = (const float*)d_in[0];
    const int*   faces  = (const int*)d_in[1];
    const float* points = (const float*)d_in[2];
    float* out = (float*)d_out;

    char* ws = (char*)d_ws;
    unsigned long long* best = (unsigned long long*)(ws + WS_BEST);
    uint4*    sortP  = (uint4*)(ws + WS_SORTP);
    unsigned* histP  = (unsigned*)(ws + WS_HISTP);
    unsigned* histF  = (unsigned*)(ws + WS_HISTF);
    unsigned* histFC = (unsigned*)(ws + WS_HISTFC);
    float4* fA    = (float4*)(ws + WS_FA);
    float4* fB    = (float4*)(ws + WS_FB);
    float4* fC    = (float4*)(ws + WS_FC);
    float4* fSph  = (float4*)(ws + WS_FSPH);
    float4* fScan = (float4*)(ws + WS_FSCAN);
    float2* fK    = (float2*)(ws + WS_FK);

    hipMemsetAsync(best, 0xFF, (size_t)PTOT * sizeof(unsigned long long), stream);
    hipMemsetAsync(histP, 0, 2 * (size_t)NBINS * sizeof(unsigned), stream);
    hipMemsetAsync(out, 0, sizeof(float), stream);

    hist_kernel<<<128, BLOCK, 0, stream>>>(verts, faces, points, histP, histF);
    scan_kernel<<<2, 256, 0, stream>>>(histP, histF, histFC);
    scatter_build_kernel<<<128, BLOCK, 0, stream>>>(verts, faces, points,
        histP, histF, sortP, fA, fB, fC, fSph, fScan, fK);

    dim3 grid(PTOT / BLOCK, NCH);
    sdf_main_kernel<<<grid, BLOCK, 0, stream>>>(sortP, histFC,
        fA, fB, fC, fSph, fScan, fK, best);
    sdf_final_kernel<<<PTOT / BLOCK, BLOCK, 0, stream>>>(best, out);
}

// Round 8
// 366.737 us; speedup vs baseline: 4.1614x; 1.0123x over previous
//
#include <hip/hip_runtime.h>
#include <math.h>

// MeshSDFLoss: P=16384 points vs F=16384 triangles, min sqdist + argmin + loss.
// Outputs (flat float32): [0]=loss, [1..P]=dist, [1+P..1+2P]=assoc (as float).
//
// R8: R7 semantics (identical margins/certificates/exec), restructured:
//  - NCH=32 (2048 blocks -> 8 blocks/CU grid cap).
//  - LDS stages only scan+filter data (nh/d0, kp/J, sphere) = 18 KB;
//    exec gathers fA/fB/fC from global (L2-resident tables).
//  - 1 seed exec per (point, chunk) from the point's 32-face Morton window.
//  - exec_pair BIT-EXACT vs numpy fp32 reference (R2-verified).
//  - Tie-break: packed (distbits<<32)|origIdx u64 min == np.argmin first-index.

#define PTOT 16384
#define FTOT 16384
#define NBINS 4096
#define BLOCK 256
#define NCH 32
#define FCHUNK (FTOT / NCH)   // 512
#define TILE 256
#define QD 16

// ws layout (bytes)
#define WS_BEST    0           // u64[16384]   131072
#define WS_SORTP   131072      // uint4[16384] 262144
#define WS_HISTP   393216      // u32[4096]
#define WS_HISTF   409600      // u32[4096]
#define WS_HISTFC  425984      // u32[4096]
#define WS_FA      442368      // float4[16384] {a, origIdxBits}
#define WS_FB      704512      // float4[16384]
#define WS_FC      966656      // float4[16384]
#define WS_FSPH    1228800     // float4[16384] {centroid, rf}
#define WS_FSCAN   1490944     // float4[16384] {nh, md0}
#define WS_FK      1753088     // float2[16384] {kp, J}

__device__ __forceinline__ unsigned morton12(float x, float y, float z) {
    int ix = (int)(x * 16.0f); ix = ix < 0 ? 0 : (ix > 15 ? 15 : ix);
    int iy = (int)(y * 16.0f); iy = iy < 0 ? 0 : (iy > 15 ? 15 : iy);
    int iz = (int)(z * 16.0f); iz = iz < 0 ? 0 : (iz > 15 ? 15 : iz);
    unsigned code = 0;
#pragma unroll
    for (int k = 0; k < 4; ++k) {
        code |= (((unsigned)(ix >> k) & 1u) << (3 * k + 2))
              | (((unsigned)(iy >> k) & 1u) << (3 * k + 1))
              | (((unsigned)(iz >> k) & 1u) << (3 * k + 0));
    }
    return code;
}

// Bit-exact point-triangle squared distance (reference-identical rounding).
__device__ __forceinline__ float exec_pair(
    float px, float py, float pz,
    float ax, float ay, float az,
    float bx, float by, float bz,
    float cx, float cy, float cz)
{
#pragma clang fp contract(off)
    const float abx = __fsub_rn(bx, ax), aby = __fsub_rn(by, ay), abz = __fsub_rn(bz, az);
    const float acx = __fsub_rn(cx, ax), acy = __fsub_rn(cy, ay), acz = __fsub_rn(cz, az);
    const float cbx = __fsub_rn(cx, bx), cby = __fsub_rn(cy, by), cbz = __fsub_rn(cz, bz);

    const float apx = __fsub_rn(px, ax), apy = __fsub_rn(py, ay), apz = __fsub_rn(pz, az);
    const float d1 = __fadd_rn(__fadd_rn(__fmul_rn(abx, apx), __fmul_rn(aby, apy)), __fmul_rn(abz, apz));
    const float d2 = __fadd_rn(__fadd_rn(__fmul_rn(acx, apx), __fmul_rn(acy, apy)), __fmul_rn(acz, apz));
    const float bpx = __fsub_rn(px, bx), bpy = __fsub_rn(py, by), bpz = __fsub_rn(pz, bz);
    const float d3 = __fadd_rn(__fadd_rn(__fmul_rn(abx, bpx), __fmul_rn(aby, bpy)), __fmul_rn(abz, bpz));
    const float d4 = __fadd_rn(__fadd_rn(__fmul_rn(acx, bpx), __fmul_rn(acy, bpy)), __fmul_rn(acz, bpz));
    const float cpx = __fsub_rn(px, cx), cpy = __fsub_rn(py, cy), cpz = __fsub_rn(pz, cz);
    const float d5 = __fadd_rn(__fadd_rn(__fmul_rn(abx, cpx), __fmul_rn(aby, cpy)), __fmul_rn(abz, cpz));
    const float d6 = __fadd_rn(__fadd_rn(__fmul_rn(acx, cpx), __fmul_rn(acy, cpy)), __fmul_rn(acz, cpz));

    const float vc_ = __fsub_rn(__fmul_rn(d1, d4), __fmul_rn(d3, d2));
    const float vb_ = __fsub_rn(__fmul_rn(d5, d2), __fmul_rn(d1, d6));
    const float va_ = __fsub_rn(__fmul_rn(d3, d6), __fmul_rn(d5, d4));

    const float den_ab = __fsub_rn(d1, d3);
    const float den_ac = __fsub_rn(d2, d6);
    const float t43    = __fsub_rn(d4, d3);
    const float t56    = __fsub_rn(d5, d6);
    const float den_bc = __fadd_rn(t43, t56);
    const float den_in = __fadd_rn(__fadd_rn(va_, vb_), vc_);

    const bool f_a  = (d1 <= 0.0f) && (d2 <= 0.0f);
    const bool f_b  = (d3 >= 0.0f) && (d4 <= d3);
    const bool f_c  = (d6 >= 0.0f) && (d5 <= d6);
    const bool f_ab = (vc_ <= 0.0f) && (d1 >= 0.0f) && (d3 <= 0.0f);
    const bool f_ac = (vb_ <= 0.0f) && (d2 >= 0.0f) && (d6 <= 0.0f);
    const bool f_bc = (va_ <= 0.0f) && (t43 >= 0.0f) && (t56 >= 0.0f);
    const bool vert = f_a || f_b || f_c;
    const bool e_ab = f_ab && !vert;
    const bool e_ac = f_ac && !vert && !f_ab;
    const bool e_bc = f_bc && !vert && !f_ab && !f_ac;
    const bool inte = !vert && !f_ab && !f_ac && !f_bc;

    const float num  = e_ab ? d1 : (e_ac ? d2 : (e_bc ? t43 : 1.0f));
    const float denr = e_ab ? den_ab : (e_ac ? den_ac : (e_bc ? den_bc : den_in));
    const float den  = (denr != 0.0f) ? denr : 1.0f;
    const float t    = __fdiv_rn(num, den);

    const float v_in = __fmul_rn(vb_, t);
    const float w_in = __fmul_rn(vc_, t);

    const float s1 = vert ? 0.0f : (inte ? v_in : t);
    const float s2 = inte ? w_in : 0.0f;
    const bool  sel_b = (!f_a && f_b) || e_bc;
    const bool  sel_c = !f_a && !f_b && f_c;
    const float e1x = e_ac ? acx : (e_bc ? cbx : abx);
    const float e1y = e_ac ? acy : (e_bc ? cby : aby);
    const float e1z = e_ac ? acz : (e_bc ? cbz : abz);
    const float bsx = sel_b ? bx : (sel_c ? cx : ax);
    const float bsy = sel_b ? by : (sel_c ? cy : ay);
    const float bsz = sel_b ? bz : (sel_c ? cz : az);
    const float qx = __fadd_rn(__fadd_rn(bsx, __fmul_rn(e1x, s1)), __fmul_rn(acx, s2));
    const float qy = __fadd_rn(__fadd_rn(bsy, __fmul_rn(e1y, s1)), __fmul_rn(acy, s2));
    const float qz = __fadd_rn(__fadd_rn(bsz, __fmul_rn(e1z, s1)), __fmul_rn(acz, s2));

    const float dxx = __fsub_rn(px, qx), dyy = __fsub_rn(py, qy), dzz = __fsub_rn(pz, qz);
    return __fadd_rn(__fadd_rn(__fmul_rn(dxx, dxx), __fmul_rn(dyy, dyy)), __fmul_rn(dzz, dzz));
}

// ---- prep: histograms (blocks 0..63: points, 64..127: faces) ----
__global__ __launch_bounds__(BLOCK) void hist_kernel(
    const float* __restrict__ verts, const int* __restrict__ faces,
    const float* __restrict__ points,
    unsigned* __restrict__ histP, unsigned* __restrict__ histF)
{
    const int b = blockIdx.x;
    if (b < 64) {
        const int p = b * BLOCK + threadIdx.x;
        atomicAdd(&histP[morton12(points[p*3], points[p*3+1], points[p*3+2])], 1u);
    } else {
        const int f = (b - 64) * BLOCK + threadIdx.x;
        const int i0 = faces[f*3+0], i1 = faces[f*3+1], i2 = faces[f*3+2];
        const float mx = (verts[i0*3+0] + verts[i1*3+0] + verts[i2*3+0]) * (1.0f/3.0f);
        const float my = (verts[i0*3+1] + verts[i1*3+1] + verts[i2*3+1]) * (1.0f/3.0f);
        const float mz = (verts[i0*3+2] + verts[i1*3+2] + verts[i2*3+2]) * (1.0f/3.0f);
        atomicAdd(&histF[morton12(mx, my, mz)], 1u);
    }
}

__global__ __launch_bounds__(256) void scan_kernel(
    unsigned* __restrict__ histP, unsigned* __restrict__ histF,
    unsigned* __restrict__ histFC)
{
    unsigned* h = (blockIdx.x == 0) ? histP : histF;
    __shared__ unsigned ps[256];
    const int t = threadIdx.x;
    unsigned local[16];
    unsigned run = 0;
#pragma unroll
    for (int i = 0; i < 16; ++i) { unsigned v = h[t*16+i]; local[i] = run; run += v; }
    ps[t] = run;
    __syncthreads();
    for (int off = 1; off < 256; off <<= 1) {
        unsigned v = (t >= off) ? ps[t - off] : 0u;
        __syncthreads();
        ps[t] += v;
        __syncthreads();
    }
    const unsigned base = (t == 0) ? 0u : ps[t-1];
#pragma unroll
    for (int i = 0; i < 16; ++i) {
        const unsigned off = base + local[i];
        h[t*16+i] = off;
        if (blockIdx.x == 1) histFC[t*16+i] = off;
    }
}

// ---- prep: scatter points + scatter/build faces (fp64 certified metadata) ----
__global__ __launch_bounds__(BLOCK) void scatter_build_kernel(
    const float* __restrict__ verts, const int* __restrict__ faces,
    const float* __restrict__ points,
    unsigned* __restrict__ histP, unsigned* __restrict__ histF,
    uint4* __restrict__ sortP,
    float4* __restrict__ fA, float4* __restrict__ fB, float4* __restrict__ fC,
    float4* __restrict__ fSph, float4* __restrict__ fScan,
    float2* __restrict__ fK)
{
    const int b = blockIdx.x;
    if (b < 64) {
        const int p = b * BLOCK + threadIdx.x;
        const float x = points[p*3], y = points[p*3+1], z = points[p*3+2];
        const unsigned pos = atomicAdd(&histP[morton12(x, y, z)], 1u);
        sortP[pos] = make_uint4(__float_as_uint(x), __float_as_uint(y),
                                __float_as_uint(z), (unsigned)p);
        return;
    }
    const int f = (b - 64) * BLOCK + threadIdx.x;
    const int i0 = faces[f*3+0], i1 = faces[f*3+1], i2 = faces[f*3+2];
    const float ax = verts[i0*3+0], ay = verts[i0*3+1], az = verts[i0*3+2];
    const float bx = verts[i1*3+0], by = verts[i1*3+1], bz = verts[i1*3+2];
    const float cx = verts[i2*3+0], cy = verts[i2*3+1], cz = verts[i2*3+2];
    const float mx = (ax+bx+cx) * (1.0f/3.0f);
    const float my = (ay+by+cy) * (1.0f/3.0f);
    const float mz = (az+bz+cz) * (1.0f/3.0f);
    const unsigned pos = atomicAdd(&histF[morton12(mx, my, mz)], 1u);

    fA[pos] = make_float4(ax, ay, az, __uint_as_float((unsigned)f));
    fB[pos] = make_float4(bx, by, bz, 0.0f);
    fC[pos] = make_float4(cx, cy, cz, 0.0f);

    const double abx = (double)bx-ax, aby = (double)by-ay, abz = (double)bz-az;
    const double acx = (double)cx-ax, acy = (double)cy-ay, acz = (double)cz-az;
    const double cbx = (double)cx-bx, cby = (double)cy-by, cbz = (double)cz-bz;
    const double nx = aby*acz - abz*acy;
    const double ny = abz*acx - abx*acz;
    const double nz = abx*acy - aby*acx;
    const double nn = nx*nx + ny*ny + nz*nz;
    const double e1 = sqrt(abx*abx + aby*aby + abz*abz);
    const double e2 = sqrt(acx*acx + acy*acy + acz*acz);
    const double e3 = sqrt(cbx*cbx + cby*cby + cbz*cbz);
    const double maxe = fmax(e1, fmax(e2, e3));
    const double mine = fmin(e1, fmin(e2, e3));
    const double mine2 = mine * mine;
    const double maxe2 = maxe * maxe;
    const double maxe3 = maxe2 * maxe;

    const bool exempt = !(nn > 1e-5 * maxe2) || !(mine2 > 5e-6 * maxe);

    float4 sc;
    float kp, J;
    if (!exempt) {
        const double rin = 1.0 / sqrt(nn);
        sc.x = (float)(nx * rin);
        sc.y = (float)(ny * rin);
        sc.z = (float)(nz * rin);
        sc.w = (float)(-(nx*rin*ax + ny*rin*ay + nz*rin*az));
        kp = (float)fmin(1e4, 3e-5 * maxe3 / nn + 2e-5);
        J  = (float)fmin(1e4, 1.2 * (6e-5 * maxe3 / nn
                                   + 5e-5 * maxe2 / mine2
                                   + 2.6e-6 * maxe / mine
                                   + 3.2e-3));
    } else {
        sc = make_float4(0.0f, 0.0f, 0.0f, 0.0f);  // pd=0 -> always in band
        kp = 1e4f;
        J  = 1e30f;                                 // never drain-skipped
    }
    fScan[pos] = sc;
    fK[pos] = make_float2(kp, J);

    const double ra = sqrt(((double)ax-mx)*((double)ax-mx) + ((double)ay-my)*((double)ay-my) + ((double)az-mz)*((double)az-mz));
    const double rb = sqrt(((double)bx-mx)*((double)bx-mx) + ((double)by-my)*((double)by-my) + ((double)bz-mz)*((double)bz-mz));
    const double rc = sqrt(((double)cx-mx)*((double)cx-mx) + ((double)cy-my)*((double)cy-my) + ((double)cz-mz)*((double)cz-mz));
    const float rf = (float)(fmax(ra, fmax(rb, rc)) * 1.0002 + 2e-4);
    fSph[pos] = make_float4(mx, my, mz, rf);
}

// ---- main ----
__global__ __launch_bounds__(BLOCK) void sdf_main_kernel(
    const uint4* __restrict__ sortP,
    const unsigned* __restrict__ histFC,
    const float4* __restrict__ fA, const float4* __restrict__ fB,
    const float4* __restrict__ fC, const float4* __restrict__ fSph,
    const float4* __restrict__ fScan, const float2* __restrict__ fK,
    unsigned long long* __restrict__ best)
{
    __shared__ float4 sScan[TILE];     // 4 KB
    __shared__ float4 sSph[TILE];      // 4 KB
    __shared__ float2 sK[TILE];        // 2 KB
    __shared__ unsigned short sQ[TILE * QD];  // 8 KB

    const int tid = threadIdx.x;
    const uint4 sp = sortP[blockIdx.x * BLOCK + tid];
    const float px = __uint_as_float(sp.x);
    const float py = __uint_as_float(sp.y);
    const float pz = __uint_as_float(sp.z);
    const int  pid = (int)sp.w;

    // --- seed: 1 face of the 32-face Morton window (chunks jointly cover it) ---
    unsigned long long bestPk = ~0ull;
    {
        const unsigned code = morton12(px, py, pz);
        int w = (int)histFC[code] - 16;
        w = w < 0 ? 0 : (w > FTOT - 32 ? FTOT - 32 : w);
        const int i = w + (int)blockIdx.y;       // NCH==32 covers the window
        const float4 A = fA[i], B = fB[i], C = fC[i];
        const float d = exec_pair(px, py, pz, A.x, A.y, A.z, B.x, B.y, B.z, C.x, C.y, C.z);
        bestPk = ((unsigned long long)__float_as_uint(d) << 32) | __float_as_uint(A.w);
    }
    {
        const unsigned long long old = atomicMin(&best[pid], bestPk);
        if (old < bestPk) bestPk = old;
    }
    float pruneS = sqrtf(__uint_as_float((unsigned)(bestPk >> 32)));
    float thr    = __fmaf_rn(pruneS, 1.005f, 1e-3f);

    const int fbase = (int)blockIdx.y * FCHUNK;
    int cnt = 0;

    auto drain = [&]() {
        for (int k = 0; ; ++k) {
            if (!__ballot(k < cnt)) break;
            if (k < cnt) {
                const int j = (int)sQ[tid * QD + k];
                const float4 sc = sScan[j];
                const float4 S  = sSph[j];
                const float dx = px - S.x, dy = py - S.y, dz = pz - S.z;
                const float dcc2 = __fmaf_rn(dx, dx, __fmaf_rn(dy, dy, dz * dz));
                const float pdc  = __fmaf_rn(sc.x, dx, __fmaf_rn(sc.y, dy, sc.z * dz));
                const float pd   = __fmaf_rn(sc.x, px, __fmaf_rn(sc.y, py, __fmaf_rn(sc.z, pz, sc.w)));
                const float aa   = fmaxf(fabsf(pd) - 1e-5f, 0.0f);
                const float lat2 = fmaxf(dcc2 - pdc * pdc, 0.0f);
                const float lat  = fmaxf(sqrtf(lat2) * 0.999f - S.w - 1e-4f, 0.0f);
                const float lhs  = __fmaf_rn(aa, aa, lat * lat);
                const float rhs  = thr + sK[j].y;   // thr + J (inf-safe)
                // NaN lhs/rhs -> compare false -> execute (conservative)
                if (!(lhs > rhs * rhs)) {
                    const int gi = fbase /*tile base added below*/ + j;  // corrected per-tile below
                    (void)gi;
                    const int fi = (int)sQ[tid * QD + k] + 0;  // placeholder, real index passed via sQ basing
                    (void)fi;
                    // NOTE: sQ stores tile-local j; global index = tileBase + j,
                    // tileBase is wave-uniform and captured by reference below.
                }
            }
        }
        cnt = 0;
    };
    (void)drain; // replaced by the tile-aware drain below

    for (int t0 = 0; t0 < FCHUNK; t0 += TILE) {
        const int tileBase = fbase + t0;
        __syncthreads();
        {
            const int g = tileBase + tid;
            sScan[tid] = fScan[g];
            sSph[tid]  = fSph[g];
            sK[tid]    = fK[g];
        }
        __syncthreads();

        // fold in cross-chunk progress
        {
            const unsigned long long gb =
                __hip_atomic_load(&best[pid], __ATOMIC_RELAXED, __HIP_MEMORY_SCOPE_AGENT);
            if (gb < bestPk) bestPk = gb;
            pruneS = fminf(pruneS, sqrtf(__uint_as_float((unsigned)(bestPk >> 32))));
            thr    = __fmaf_rn(pruneS, 1.005f, 1e-3f);
        }

        auto drainT = [&]() {
            for (int k = 0; ; ++k) {
                if (!__ballot(k < cnt)) break;
                if (k < cnt) {
                    const int j = (int)sQ[tid * QD + k];
                    const float4 sc = sScan[j];
                    const float4 S  = sSph[j];
                    const float dx = px - S.x, dy = py - S.y, dz = pz - S.z;
                    const float dcc2 = __fmaf_rn(dx, dx, __fmaf_rn(dy, dy, dz * dz));
                    const float pdc  = __fmaf_rn(sc.x, dx, __fmaf_rn(sc.y, dy, sc.z * dz));
                    const float pd   = __fmaf_rn(sc.x, px, __fmaf_rn(sc.y, py, __fmaf_rn(sc.z, pz, sc.w)));
                    const float aa   = fmaxf(fabsf(pd) - 1e-5f, 0.0f);
                    const float lat2 = fmaxf(dcc2 - pdc * pdc, 0.0f);
                    const float lat  = fmaxf(sqrtf(lat2) * 0.999f - S.w - 1e-4f, 0.0f);
                    const float lhs  = __fmaf_rn(aa, aa, lat * lat);
                    const float rhs  = thr + sK[j].y;   // thr + J (inf-safe)
                    if (!(lhs > rhs * rhs)) {
                        const int fi = tileBase + j;
                        const float4 A = fA[fi], B = fB[fi], C = fC[fi];
                        const float d = exec_pair(px, py, pz,
                            A.x, A.y, A.z, B.x, B.y, B.z, C.x, C.y, C.z);
                        const unsigned long long pk =
                            ((unsigned long long)__float_as_uint(d) << 32) | __float_as_uint(A.w);
                        if (pk < bestPk) {
                            bestPk = pk;
                            pruneS = fminf(pruneS, sqrtf(d));
                            thr    = __fmaf_rn(pruneS, 1.005f, 1e-3f);
                        }
                    }
                }
            }
            cnt = 0;
        };

        for (int j0 = 0; j0 < TILE; j0 += 8) {
#pragma unroll
            for (int j = j0; j < j0 + 8; ++j) {
                const float4 sc = sScan[j];
                const float pd = __fmaf_rn(sc.x, px, __fmaf_rn(sc.y, py, __fmaf_rn(sc.z, pz, sc.w)));
                // NaN-safe: NaN pd -> in band -> queued
                const bool inband = !(fabsf(pd) > (thr + sK[j].x));
                if (inband) { sQ[tid * QD + cnt] = (unsigned short)j; ++cnt; }
            }
            if (__any(cnt >= QD - 8)) drainT();
        }
        drainT();
    }

    atomicMin(&best[pid], bestPk);
}

__global__ __launch_bounds__(BLOCK) void sdf_final_kernel(
    const unsigned long long* __restrict__ best, float* __restrict__ out)
{
    __shared__ float wsum[BLOCK / 64];
    const int p = blockIdx.x * BLOCK + threadIdx.x;
    const unsigned long long v = best[p];
    const float d = __uint_as_float((unsigned)(v >> 32));
    const int idx = (int)(unsigned)(v & 0xffffffffull);
    out[1 + p] = d;
    out[1 + PTOT + p] = (float)idx;

    float s = d;
    for (int off = 32; off > 0; off >>= 1) s += __shfl_down(s, off, 64);
    const int lane = threadIdx.x & 63;
    const int w = threadIdx.x >> 6;
    if (lane == 0) wsum[w] = s;
    __syncthreads();
    if (threadIdx.x == 0) {
        float tsum = 0.0f;
        for (int i = 0; i < BLOCK / 64; ++i) tsum += wsum[i];
        atomicAdd(&out[0], tsum);
    }
}

extern "C" void kernel_launch(void* const* d_in, const int* in_sizes, int n_in,
                              void* d_out, int out_size, void* d_ws, size_t ws_size,
                              hipStream_t stream) {
    const float* verts  = (const float*)d_in[0];
    const int*   faces  = (const int*)d_in[1];
    const float* points = (const float*)d_in[2];
    float* out = (float*)d_out;

    char* ws = (char*)d_ws;
    unsigned long long* best = (unsigned long long*)(ws + WS_BEST);
    uint4*    sortP  = (uint4*)(ws + WS_SORTP);
    unsigned* histP  = (unsigned*)(ws + WS_HISTP);
    unsigned* histF  = (unsigned*)(ws + WS_HISTF);
    unsigned* histFC = (unsigned*)(ws + WS_HISTFC);
    float4* fA    = (float4*)(ws + WS_FA);
    float4* fB    = (float4*)(ws + WS_FB);
    float4* fC    = (float4*)(ws + WS_FC);
    float4* fSph  = (float4*)(ws + WS_FSPH);
    float4* fScan = (float4*)(ws + WS_FSCAN);
    float2* fK    = (float2*)(ws + WS_FK);

    hipMemsetAsync(best, 0xFF, (size_t)PTOT * sizeof(unsigned long long), stream);
    hipMemsetAsync(histP, 0, 2 * (size_t)NBINS * sizeof(unsigned), stream);
    hipMemsetAsync(out, 0, sizeof(float), stream);

    hist_kernel<<<128, BLOCK, 0, stream>>>(verts, faces, points, histP, histF);
    scan_kernel<<<2, 256, 0, stream>>>(histP, histF, histFC);
    scatter_build_kernel<<<128, BLOCK, 0, stream>>>(verts, faces, points,
        histP, histF, sortP, fA, fB, fC, fSph, fScan, fK);

    dim3 grid(PTOT / BLOCK, NCH);
    sdf_main_kernel<<<grid, BLOCK, 0, stream>>>(sortP, histFC,
        fA, fB, fC, fSph, fScan, fK, best);
    sdf_final_kernel<<<PTOT / BLOCK, BLOCK, 0, stream>>>(best, out);
}